// Round 1
// baseline (1712.310 us; speedup 1.0000x reference)
//
#include <hip/hip_runtime.h>
#include <cstddef>

#define DIM 2048
#define NROWS 8192
#define NL 3
#define DEPTH 5
#define CF_EPS 0.01f

#define BM 128
#define BN 128
#define BK 16
#define LDA 132   // padded leading dim for LDS tiles

// C[r][n] = sum_d X[r][d] * W[n][d]; W is U_w for n<2048 (-> outLin=d_out),
// gate_w for n>=2048 (-> outGate=ws). Both weight matrices are [out,in] row-major,
// so this is the K-contiguous "NT" GEMM on both operands.
__global__ __launch_bounds__(256) void sgemm_dual(
    const float* __restrict__ X,
    const float* __restrict__ Uw,
    const float* __restrict__ Gw,
    float* __restrict__ outLin,
    float* __restrict__ outGate)
{
    __shared__ float As[BK][LDA];
    __shared__ float Bs[BK][LDA];

    const int tid = threadIdx.x;
    const int n0 = blockIdx.x * BN;
    const int m0 = blockIdx.y * BM;
    const bool isGate = (n0 >= DIM);
    const float* W = isGate ? Gw : Uw;
    float* C = isGate ? outGate : outLin;
    const int nb = isGate ? (n0 - DIM) : n0;

    // global->LDS staging indices: 256 threads, each loads 2x float4 of A and B
    const int lr = tid >> 2;          // 0..63
    const int lc = (tid & 3) << 2;    // 0,4,8,12

    const float* pa0 = X + (size_t)(m0 + lr) * DIM + lc;
    const float* pa1 = X + (size_t)(m0 + lr + 64) * DIM + lc;
    const float* pb0 = W + (size_t)(nb + lr) * DIM + lc;
    const float* pb1 = W + (size_t)(nb + lr + 64) * DIM + lc;

    // compute indices: 16x16 thread grid, 8x8 micro-tile each
    const int tx = tid & 15;
    const int ty = tid >> 4;

    float acc[8][8];
    #pragma unroll
    for (int i = 0; i < 8; ++i)
        #pragma unroll
        for (int j = 0; j < 8; ++j) acc[i][j] = 0.f;

    for (int k0 = 0; k0 < DIM; k0 += BK) {
        const float4 a0 = *(const float4*)(pa0 + k0);
        const float4 a1 = *(const float4*)(pa1 + k0);
        const float4 b0 = *(const float4*)(pb0 + k0);
        const float4 b1 = *(const float4*)(pb1 + k0);
        __syncthreads();
        As[lc + 0][lr] = a0.x; As[lc + 1][lr] = a0.y; As[lc + 2][lr] = a0.z; As[lc + 3][lr] = a0.w;
        As[lc + 0][lr + 64] = a1.x; As[lc + 1][lr + 64] = a1.y; As[lc + 2][lr + 64] = a1.z; As[lc + 3][lr + 64] = a1.w;
        Bs[lc + 0][lr] = b0.x; Bs[lc + 1][lr] = b0.y; Bs[lc + 2][lr] = b0.z; Bs[lc + 3][lr] = b0.w;
        Bs[lc + 0][lr + 64] = b1.x; Bs[lc + 1][lr + 64] = b1.y; Bs[lc + 2][lr + 64] = b1.z; Bs[lc + 3][lr + 64] = b1.w;
        __syncthreads();
        #pragma unroll
        for (int kk = 0; kk < BK; ++kk) {
            float av[8], bv[8];
            *(float4*)&av[0] = *(const float4*)&As[kk][ty * 8];
            *(float4*)&av[4] = *(const float4*)&As[kk][ty * 8 + 4];
            *(float4*)&bv[0] = *(const float4*)&Bs[kk][tx * 8];
            *(float4*)&bv[4] = *(const float4*)&Bs[kk][tx * 8 + 4];
            #pragma unroll
            for (int i = 0; i < 8; ++i)
                #pragma unroll
                for (int j = 0; j < 8; ++j)
                    acc[i][j] = fmaf(av[i], bv[j], acc[i][j]);
        }
    }

    #pragma unroll
    for (int i = 0; i < 8; ++i) {
        float* crow = C + (size_t)(m0 + ty * 8 + i) * DIM + nb + tx * 8;
        *(float4*)crow       = make_float4(acc[i][0], acc[i][1], acc[i][2], acc[i][3]);
        *(float4*)(crow + 4) = make_float4(acc[i][4], acc[i][5], acc[i][6], acc[i][7]);
    }
}

// One block per row r: gated = sigmoid(g)*x; a[l,k] = <gated, ladder_w[l,k,:]>;
// z[l] = a0 + continued fraction; Out[r,:] += z @ V_w^T   (Out holds linear_out).
__global__ __launch_bounds__(256) void ladder_epilogue(
    const float* __restrict__ X,
    const float* __restrict__ G,
    const float* __restrict__ Lw,   // (3,6,2048)
    const float* __restrict__ Vw,   // (2048,3)
    float* __restrict__ Out)
{
    const int r = blockIdx.x;
    const int tid = threadIdx.x;
    const int d0 = tid * 8;
    const float* xrow = X + (size_t)r * DIM;
    const float* grow = G + (size_t)r * DIM;

    const float4 xv0 = *(const float4*)(xrow + d0);
    const float4 xv1 = *(const float4*)(xrow + d0 + 4);
    const float4 gv0 = *(const float4*)(grow + d0);
    const float4 gv1 = *(const float4*)(grow + d0 + 4);

    float gated[8];
    {
        const float gx[8] = {gv0.x, gv0.y, gv0.z, gv0.w, gv1.x, gv1.y, gv1.z, gv1.w};
        const float xx[8] = {xv0.x, xv0.y, xv0.z, xv0.w, xv1.x, xv1.y, xv1.z, xv1.w};
        #pragma unroll
        for (int j = 0; j < 8; ++j) {
            const float s = 1.0f / (1.0f + __expf(-gx[j]));
            gated[j] = s * xx[j];
        }
    }

    float part[NL * (DEPTH + 1)];
    #pragma unroll
    for (int lk = 0; lk < NL * (DEPTH + 1); ++lk) {
        const float* lrow = Lw + (size_t)lk * DIM + d0;
        const float4 w0 = *(const float4*)lrow;
        const float4 w1 = *(const float4*)(lrow + 4);
        part[lk] = gated[0] * w0.x + gated[1] * w0.y + gated[2] * w0.z + gated[3] * w0.w
                 + gated[4] * w1.x + gated[5] * w1.y + gated[6] * w1.z + gated[7] * w1.w;
    }

    // wave (64-lane) reduction, then cross-wave via LDS
    #pragma unroll
    for (int off = 32; off > 0; off >>= 1) {
        #pragma unroll
        for (int lk = 0; lk < NL * (DEPTH + 1); ++lk)
            part[lk] += __shfl_down(part[lk], off, 64);
    }

    __shared__ float red[4][NL * (DEPTH + 1)];
    __shared__ float zsh[NL];
    const int wave = tid >> 6;
    const int lane = tid & 63;
    if (lane == 0) {
        #pragma unroll
        for (int lk = 0; lk < NL * (DEPTH + 1); ++lk) red[wave][lk] = part[lk];
    }
    __syncthreads();
    if (tid < NL) {
        float a[DEPTH + 1];
        #pragma unroll
        for (int k = 0; k < DEPTH + 1; ++k)
            a[k] = red[0][tid * 6 + k] + red[1][tid * 6 + k]
                 + red[2][tid * 6 + k] + red[3][tid * 6 + k];
        float f = 0.f;
        #pragma unroll
        for (int k = DEPTH - 1; k >= 0; --k) {
            float denom = 1.f + f;
            if (fabsf(denom) < CF_EPS) denom = (denom >= 0.f) ? CF_EPS : -CF_EPS;
            f = a[k + 1] / denom;
        }
        zsh[tid] = a[0] + f;
    }
    __syncthreads();
    const float z0 = zsh[0], z1 = zsh[1], z2 = zsh[2];

    float* orow = Out + (size_t)r * DIM + d0;
    const float4 o0 = *(const float4*)orow;
    const float4 o1 = *(const float4*)(orow + 4);
    float ov[8] = {o0.x, o0.y, o0.z, o0.w, o1.x, o1.y, o1.z, o1.w};
    #pragma unroll
    for (int j = 0; j < 8; ++j) {
        const float* vp = Vw + (size_t)(d0 + j) * NL;
        ov[j] += z0 * vp[0] + z1 * vp[1] + z2 * vp[2];
    }
    *(float4*)orow       = make_float4(ov[0], ov[1], ov[2], ov[3]);
    *(float4*)(orow + 4) = make_float4(ov[4], ov[5], ov[6], ov[7]);
}

extern "C" void kernel_launch(void* const* d_in, const int* in_sizes, int n_in,
                              void* d_out, int out_size, void* d_ws, size_t ws_size,
                              hipStream_t stream) {
    const float* X  = (const float*)d_in[0];
    const float* Uw = (const float*)d_in[1];
    const float* Gw = (const float*)d_in[2];
    const float* Lw = (const float*)d_in[3];
    const float* Vw = (const float*)d_in[4];
    float* out  = (float*)d_out;
    float* gbuf = (float*)d_ws;   // gate logits: 8192*2048 floats = 64 MB

    dim3 grid(2 * DIM / BN, NROWS / BM);
    sgemm_dual<<<grid, dim3(256), 0, stream>>>(X, Uw, Gw, out, gbuf);
    ladder_epilogue<<<dim3(NROWS), dim3(256), 0, stream>>>(X, gbuf, Lw, Vw, out);
}

// Round 2
// 574.244 us; speedup vs baseline: 2.9818x; 2.9818x over previous
//
#include <hip/hip_runtime.h>
#include <cstdint>
#include <cstddef>

#define DIM 2048
#define NROWS 8192
#define NL 3
#define DEPTH 5
#define CF_EPS 0.01f

// ---------------------------------------------------------------- MFMA GEMM
typedef __attribute__((ext_vector_type(8))) __bf16 bfrag;   // 8 bf16 = 4 VGPRs
typedef __attribute__((ext_vector_type(4))) float f32x4;

typedef __attribute__((address_space(1))) void gvoid;
typedef __attribute__((address_space(3))) void lvoid;

__device__ __forceinline__ void gld_lds16(const void* g, void* l) {
    // async global->LDS, 16B per lane, dest = wave-uniform base + lane*16
    __builtin_amdgcn_global_load_lds((gvoid*)g, (lvoid*)l, 16, 0, 0);
}

// C[m][n] = sum_k A[m][k]*B[n][k]  (both K-contiguous, "NT")
// SPLIT: C = Ah*Bh + Ah*Bl + Al*Bh   (split-bf16, ~fp32-accurate logits)
// 128x128 tile, BK=32, 256 thr = 4 waves (2x2), wave = 64x64 = 4x4 MFMA tiles.
template<bool SPLIT>
__global__ __launch_bounds__(256) void mfma_gemm(
    const ushort* __restrict__ Ah, const ushort* __restrict__ Al,
    const ushort* __restrict__ Bh, const ushort* __restrict__ Bl,
    float* __restrict__ C)
{
    constexpr int BK = 32;                       // one MFMA K-depth
    __shared__ __align__(16) ushort sAh[128 * BK];
    __shared__ __align__(16) ushort sBh[128 * BK];
    __shared__ __align__(16) ushort sAl[SPLIT ? 128 * BK : 8];
    __shared__ __align__(16) ushort sBl[SPLIT ? 128 * BK : 8];

    const int tid  = threadIdx.x;
    const int wave = tid >> 6;
    const int lane = tid & 63;
    const int wm   = wave & 1;                   // wave row in 2x2
    const int wn   = wave >> 1;                  // wave col
    const int m0   = blockIdx.y * 128;
    const int n0   = blockIdx.x * 128;

    // staging: wave w covers rows [w*32, w*32+32) of each 128x32 tile,
    // 2 issues x 16 rows; lane -> row=lane>>2, 16B chunk=lane&3
    const size_t soff = (size_t)(wave * 32 + (lane >> 2)) * DIM + (lane & 3) * 8;
    const ushort* gA  = Ah + (size_t)m0 * DIM + soff;
    const ushort* gB  = Bh + (size_t)n0 * DIM + soff;
    const ushort* gAl = Al + (size_t)m0 * DIM + soff;
    const ushort* gBl = Bl + (size_t)n0 * DIM + soff;

    ushort* lA0 = &sAh[(wave * 32) * BK];
    ushort* lA1 = &sAh[(wave * 32 + 16) * BK];
    ushort* lB0 = &sBh[(wave * 32) * BK];
    ushort* lB1 = &sBh[(wave * 32 + 16) * BK];
    ushort* lAl0 = &sAl[SPLIT ? (wave * 32) * BK : 0];
    ushort* lAl1 = &sAl[SPLIT ? (wave * 32 + 16) * BK : 0];
    ushort* lBl0 = &sBl[SPLIT ? (wave * 32) * BK : 0];
    ushort* lBl1 = &sBl[SPLIT ? (wave * 32 + 16) * BK : 0];

    // fragment read: row/col-in-tile = lane&15, k-offset = (lane>>4)*8
    const int fm = lane & 15;
    const int fq = lane >> 4;

    f32x4 acc[4][4];
    #pragma unroll
    for (int i = 0; i < 4; ++i)
        #pragma unroll
        for (int j = 0; j < 4; ++j)
            acc[i][j] = (f32x4){0.f, 0.f, 0.f, 0.f};

    for (int k0 = 0; k0 < DIM; k0 += BK) {
        __syncthreads();                          // previous tile consumed
        gld_lds16(gA + k0, lA0);
        gld_lds16(gA + (size_t)16 * DIM + k0, lA1);
        gld_lds16(gB + k0, lB0);
        gld_lds16(gB + (size_t)16 * DIM + k0, lB1);
        if constexpr (SPLIT) {
            gld_lds16(gAl + k0, lAl0);
            gld_lds16(gAl + (size_t)16 * DIM + k0, lAl1);
            gld_lds16(gBl + k0, lBl0);
            gld_lds16(gBl + (size_t)16 * DIM + k0, lBl1);
        }
        __syncthreads();                          // vmcnt(0) drained by barrier

        bfrag ah[4], bh[4], al[4], bl[4];
        #pragma unroll
        for (int i = 0; i < 4; ++i) {
            ah[i] = *(const bfrag*)&sAh[(wm * 64 + i * 16 + fm) * BK + fq * 8];
            bh[i] = *(const bfrag*)&sBh[(wn * 64 + i * 16 + fm) * BK + fq * 8];
            if constexpr (SPLIT) {
                al[i] = *(const bfrag*)&sAl[(wm * 64 + i * 16 + fm) * BK + fq * 8];
                bl[i] = *(const bfrag*)&sBl[(wn * 64 + i * 16 + fm) * BK + fq * 8];
            }
        }
        #pragma unroll
        for (int i = 0; i < 4; ++i)
            #pragma unroll
            for (int j = 0; j < 4; ++j) {
                acc[i][j] = __builtin_amdgcn_mfma_f32_16x16x32_bf16(ah[i], bh[j], acc[i][j], 0, 0, 0);
                if constexpr (SPLIT) {
                    acc[i][j] = __builtin_amdgcn_mfma_f32_16x16x32_bf16(ah[i], bl[j], acc[i][j], 0, 0, 0);
                    acc[i][j] = __builtin_amdgcn_mfma_f32_16x16x32_bf16(al[i], bh[j], acc[i][j], 0, 0, 0);
                }
            }
    }

    // C/D layout: col = lane&15, row = (lane>>4)*4 + reg
    #pragma unroll
    for (int i = 0; i < 4; ++i) {
        const int rowb = m0 + wm * 64 + i * 16 + fq * 4;
        #pragma unroll
        for (int j = 0; j < 4; ++j) {
            const int col = n0 + wn * 64 + j * 16 + fm;
            #pragma unroll
            for (int r = 0; r < 4; ++r)
                C[(size_t)(rowb + r) * DIM + col] = acc[i][j][r];
        }
    }
}

// ---------------------------------------------------------------- prep
__device__ __forceinline__ ushort f2bf_bits(float f) {
    __bf16 h = (__bf16)f;                        // RNE
    return __builtin_bit_cast(unsigned short, h);
}
__device__ __forceinline__ float bfbits2f(ushort u) {
    __bf16 h = __builtin_bit_cast(__bf16, u);
    return (float)h;
}

union U16x8 { ushort u[8]; uint4 v; };

// src -> (hi = bf16(src), lo = bf16(src - hi)), 8 elems/thread
__global__ __launch_bounds__(256) void split2(const float* __restrict__ src,
                                              ushort* __restrict__ hi,
                                              ushort* __restrict__ lo)
{
    const size_t i0 = ((size_t)blockIdx.x * 256 + threadIdx.x) * 8;
    const float4 v0 = *(const float4*)(src + i0);
    const float4 v1 = *(const float4*)(src + i0 + 4);
    const float f[8] = {v0.x, v0.y, v0.z, v0.w, v1.x, v1.y, v1.z, v1.w};
    U16x8 h, l;
    #pragma unroll
    for (int j = 0; j < 8; ++j) {
        const ushort hb = f2bf_bits(f[j]);
        h.u[j] = hb;
        l.u[j] = f2bf_bits(f[j] - bfbits2f(hb));
    }
    *(uint4*)(hi + i0) = h.v;
    *(uint4*)(lo + i0) = l.v;
}

__global__ __launch_bounds__(256) void tobf16(const float* __restrict__ src,
                                              ushort* __restrict__ dst)
{
    const size_t i0 = ((size_t)blockIdx.x * 256 + threadIdx.x) * 8;
    const float4 v0 = *(const float4*)(src + i0);
    const float4 v1 = *(const float4*)(src + i0 + 4);
    const float f[8] = {v0.x, v0.y, v0.z, v0.w, v1.x, v1.y, v1.z, v1.w};
    U16x8 h;
    #pragma unroll
    for (int j = 0; j < 8; ++j) h.u[j] = f2bf_bits(f[j]);
    *(uint4*)(dst + i0) = h.v;
}

// ---------------------------------------------------------------- fp32 fallback GEMM (round-1, proven)
#define BMF 128
#define BNF 128
#define BKF 16
#define LDAF 132

__global__ __launch_bounds__(256) void sgemm_dual(
    const float* __restrict__ X,
    const float* __restrict__ Uw,
    const float* __restrict__ Gw,
    float* __restrict__ outLin,
    float* __restrict__ outGate)
{
    __shared__ float As[BKF][LDAF];
    __shared__ float Bs[BKF][LDAF];

    const int tid = threadIdx.x;
    const int n0 = blockIdx.x * BNF;
    const int m0 = blockIdx.y * BMF;
    const bool isGate = (n0 >= DIM);
    const float* W = isGate ? Gw : Uw;
    float* C = isGate ? outGate : outLin;
    const int nb = isGate ? (n0 - DIM) : n0;

    const int lr = tid >> 2;
    const int lc = (tid & 3) << 2;

    const float* pa0 = X + (size_t)(m0 + lr) * DIM + lc;
    const float* pa1 = X + (size_t)(m0 + lr + 64) * DIM + lc;
    const float* pb0 = W + (size_t)(nb + lr) * DIM + lc;
    const float* pb1 = W + (size_t)(nb + lr + 64) * DIM + lc;

    const int tx = tid & 15;
    const int ty = tid >> 4;

    float acc[8][8];
    #pragma unroll
    for (int i = 0; i < 8; ++i)
        #pragma unroll
        for (int j = 0; j < 8; ++j) acc[i][j] = 0.f;

    for (int k0 = 0; k0 < DIM; k0 += BKF) {
        const float4 a0 = *(const float4*)(pa0 + k0);
        const float4 a1 = *(const float4*)(pa1 + k0);
        const float4 b0 = *(const float4*)(pb0 + k0);
        const float4 b1 = *(const float4*)(pb1 + k0);
        __syncthreads();
        As[lc + 0][lr] = a0.x; As[lc + 1][lr] = a0.y; As[lc + 2][lr] = a0.z; As[lc + 3][lr] = a0.w;
        As[lc + 0][lr + 64] = a1.x; As[lc + 1][lr + 64] = a1.y; As[lc + 2][lr + 64] = a1.z; As[lc + 3][lr + 64] = a1.w;
        Bs[lc + 0][lr] = b0.x; Bs[lc + 1][lr] = b0.y; Bs[lc + 2][lr] = b0.z; Bs[lc + 3][lr] = b0.w;
        Bs[lc + 0][lr + 64] = b1.x; Bs[lc + 1][lr + 64] = b1.y; Bs[lc + 2][lr + 64] = b1.z; Bs[lc + 3][lr + 64] = b1.w;
        __syncthreads();
        #pragma unroll
        for (int kk = 0; kk < BKF; ++kk) {
            float av[8], bv[8];
            *(float4*)&av[0] = *(const float4*)&As[kk][ty * 8];
            *(float4*)&av[4] = *(const float4*)&As[kk][ty * 8 + 4];
            *(float4*)&bv[0] = *(const float4*)&Bs[kk][tx * 8];
            *(float4*)&bv[4] = *(const float4*)&Bs[kk][tx * 8 + 4];
            #pragma unroll
            for (int i = 0; i < 8; ++i)
                #pragma unroll
                for (int j = 0; j < 8; ++j)
                    acc[i][j] = fmaf(av[i], bv[j], acc[i][j]);
        }
    }

    #pragma unroll
    for (int i = 0; i < 8; ++i) {
        float* crow = C + (size_t)(m0 + ty * 8 + i) * DIM + nb + tx * 8;
        *(float4*)crow       = make_float4(acc[i][0], acc[i][1], acc[i][2], acc[i][3]);
        *(float4*)(crow + 4) = make_float4(acc[i][4], acc[i][5], acc[i][6], acc[i][7]);
    }
}

// ---------------------------------------------------------------- epilogue (round-1, proven)
__global__ __launch_bounds__(256) void ladder_epilogue(
    const float* __restrict__ X,
    const float* __restrict__ G,
    const float* __restrict__ Lw,
    const float* __restrict__ Vw,
    float* __restrict__ Out)
{
    const int r = blockIdx.x;
    const int tid = threadIdx.x;
    const int d0 = tid * 8;
    const float* xrow = X + (size_t)r * DIM;
    const float* grow = G + (size_t)r * DIM;

    const float4 xv0 = *(const float4*)(xrow + d0);
    const float4 xv1 = *(const float4*)(xrow + d0 + 4);
    const float4 gv0 = *(const float4*)(grow + d0);
    const float4 gv1 = *(const float4*)(grow + d0 + 4);

    float gated[8];
    {
        const float gx[8] = {gv0.x, gv0.y, gv0.z, gv0.w, gv1.x, gv1.y, gv1.z, gv1.w};
        const float xx[8] = {xv0.x, xv0.y, xv0.z, xv0.w, xv1.x, xv1.y, xv1.z, xv1.w};
        #pragma unroll
        for (int j = 0; j < 8; ++j) {
            const float s = 1.0f / (1.0f + __expf(-gx[j]));
            gated[j] = s * xx[j];
        }
    }

    float part[NL * (DEPTH + 1)];
    #pragma unroll
    for (int lk = 0; lk < NL * (DEPTH + 1); ++lk) {
        const float* lrow = Lw + (size_t)lk * DIM + d0;
        const float4 w0 = *(const float4*)lrow;
        const float4 w1 = *(const float4*)(lrow + 4);
        part[lk] = gated[0] * w0.x + gated[1] * w0.y + gated[2] * w0.z + gated[3] * w0.w
                 + gated[4] * w1.x + gated[5] * w1.y + gated[6] * w1.z + gated[7] * w1.w;
    }

    #pragma unroll
    for (int off = 32; off > 0; off >>= 1) {
        #pragma unroll
        for (int lk = 0; lk < NL * (DEPTH + 1); ++lk)
            part[lk] += __shfl_down(part[lk], off, 64);
    }

    __shared__ float red[4][NL * (DEPTH + 1)];
    __shared__ float zsh[NL];
    const int wave = tid >> 6;
    const int lane = tid & 63;
    if (lane == 0) {
        #pragma unroll
        for (int lk = 0; lk < NL * (DEPTH + 1); ++lk) red[wave][lk] = part[lk];
    }
    __syncthreads();
    if (tid < NL) {
        float a[DEPTH + 1];
        #pragma unroll
        for (int k = 0; k < DEPTH + 1; ++k)
            a[k] = red[0][tid * 6 + k] + red[1][tid * 6 + k]
                 + red[2][tid * 6 + k] + red[3][tid * 6 + k];
        float f = 0.f;
        #pragma unroll
        for (int k = DEPTH - 1; k >= 0; --k) {
            float denom = 1.f + f;
            if (fabsf(denom) < CF_EPS) denom = (denom >= 0.f) ? CF_EPS : -CF_EPS;
            f = a[k + 1] / denom;
        }
        zsh[tid] = a[0] + f;
    }
    __syncthreads();
    const float z0 = zsh[0], z1 = zsh[1], z2 = zsh[2];

    float* orow = Out + (size_t)r * DIM + d0;
    const float4 o0 = *(const float4*)orow;
    const float4 o1 = *(const float4*)(orow + 4);
    float ov[8] = {o0.x, o0.y, o0.z, o0.w, o1.x, o1.y, o1.z, o1.w};
    #pragma unroll
    for (int j = 0; j < 8; ++j) {
        const float* vp = Vw + (size_t)(d0 + j) * NL;
        ov[j] += z0 * vp[0] + z1 * vp[1] + z2 * vp[2];
    }
    *(float4*)orow       = make_float4(ov[0], ov[1], ov[2], ov[3]);
    *(float4*)(orow + 4) = make_float4(ov[4], ov[5], ov[6], ov[7]);
}

// ---------------------------------------------------------------- launch
extern "C" void kernel_launch(void* const* d_in, const int* in_sizes, int n_in,
                              void* d_out, int out_size, void* d_ws, size_t ws_size,
                              hipStream_t stream) {
    const float* X  = (const float*)d_in[0];
    const float* Uw = (const float*)d_in[1];
    const float* Gw = (const float*)d_in[2];
    const float* Lw = (const float*)d_in[3];
    const float* Vw = (const float*)d_in[4];
    float* out = (float*)d_out;

    // ws layout (bytes):
    //   gbuf fp32      @ 0          67108864
    //   Xh bf16        @ 67108864   33554432
    //   Xl bf16        @ 100663296  33554432
    //   Gwh bf16       @ 134217728   8388608
    //   Gwl bf16       @ 142606336   8388608
    //   Uwh bf16       @ 150994944   8388608
    const size_t WS_NEED = 159383552ull;
    char* ws = (char*)d_ws;
    float* gbuf = (float*)ws;

    if (ws_size >= WS_NEED) {
        ushort* Xh  = (ushort*)(ws + 67108864);
        ushort* Xl  = (ushort*)(ws + 100663296);
        ushort* Gwh = (ushort*)(ws + 134217728);
        ushort* Gwl = (ushort*)(ws + 142606336);
        ushort* Uwh = (ushort*)(ws + 150994944);

        split2<<<dim3(8192), dim3(256), 0, stream>>>(X, Xh, Xl);       // 16.78M elems
        split2<<<dim3(2048), dim3(256), 0, stream>>>(Gw, Gwh, Gwl);    // 4.19M elems
        tobf16<<<dim3(2048), dim3(256), 0, stream>>>(Uw, Uwh);

        dim3 grid(DIM / 128, NROWS / 128);   // (16, 64)
        mfma_gemm<false><<<grid, dim3(256), 0, stream>>>(Xh, Xh, Uwh, Uwh, out);
        mfma_gemm<true ><<<grid, dim3(256), 0, stream>>>(Xh, Xl, Gwh, Gwl, gbuf);
    } else {
        // fallback: round-1 fp32 path (needs only 64 MB ws)
        dim3 grid(2 * DIM / BNF, NROWS / BMF);
        sgemm_dual<<<grid, dim3(256), 0, stream>>>(X, Uw, Gw, out, gbuf);
    }
    ladder_epilogue<<<dim3(NROWS), dim3(256), 0, stream>>>(X, gbuf, Lw, Vw, out);
}